// Round 11
// baseline (64.013 us; speedup 1.0000x reference)
//
#include <hip/hip_runtime.h>
#include <math.h>

#define NPOINTS 32768
#define NPRIMS  2048
#define BLK     256

typedef float v2f __attribute__((ext_vector_type(2)));

// 64-byte record for ONE primitive, every scalar DUPLICATED so an s_load'd
// even-aligned SGPR pair feeds VOP3P packed ops as a broadcast operand.
//  q0 = (mux, mux, muy, muy)
//  q1 = (muz, muz, -amp, -amp)   amp NEGATED: folds the fract-0.5 sign flip
//  q2 = (gx,  gx,  gy,  gy )     g = -0.5*log2(e)/s^2
//  q3 = (gz,  gz,  ph,  ph )     ph in revolutions (phase/2pi)
struct PrimDup { float4 q0, q1, q2, q3; };

// Robust scalar-frequency decode (2400000000 in any plausible encoding).
__device__ __forceinline__ float read_freq(const void* p) {
    const unsigned* w = (const unsigned*)p;
    unsigned lo = w[0];
    float ff = __uint_as_float(lo);
    if (ff >= 1.0e5f && ff <= 1.0e13f) return ff;       // float32
    if (lo != 0u) return (float)lo;                      // int32-wrap / int64 lo
    double d = *(const double*)p;                        // lo==0 -> 8-byte dtype
    if (d >= 1.0e5 && d <= 1.0e13) return (float)d;      // float64
    unsigned long long v = ((unsigned long long)w[1] << 32) | lo;
    return (float)v;                                     // int64 (hi-word path)
}

__global__ __launch_bounds__(BLK) void prep_kernel(
        const float* __restrict__ pos,
        const float* __restrict__ scl,
        const float* __restrict__ amp,
        const float* __restrict__ ph,
        PrimDup* __restrict__ pd,
        float* __restrict__ kc) {
    int p = blockIdx.x * blockDim.x + threadIdx.x;
    if (p >= NPRIMS) return;
    const float KE     = -0.72134752044448169f;   // -0.5*log2(e)
    const float INV2PI =  0.15915494309189535f;
    float sx = scl[3*p+0], sy = scl[3*p+1], sz = scl[3*p+2];
    float gx = KE / (sx*sx), gy = KE / (sy*sy), gz = KE / (sz*sz);
    float pr = ph[p] * INV2PI;
    PrimDup D;
    D.q0 = make_float4(pos[3*p+0], pos[3*p+0], pos[3*p+1], pos[3*p+1]);
    D.q1 = make_float4(pos[3*p+2], pos[3*p+2], -amp[p], -amp[p]);
    D.q2 = make_float4(gx, gx, gy, gy);
    D.q3 = make_float4(gz, gz, pr, pr);
    pd[p] = D;
    if (p == 0) {
        // Taylor coeffs for sin(2*pi*v) / cos(2*pi*v), v in [-0.5, 0.5].
        // Stored in memory so the field kernel s_loads them into SGPRs:
        // VOP3P can't encode literals (R7 remat regression) and VGPR asm
        // pinning kills the s_load path (R9 regression).
        kc[0]  =   6.283185307179586f;   // s0
        kc[1]  = -41.34170224039976f;    // s1
        kc[2]  =  81.60524927607504f;    // s2
        kc[3]  = -76.70585975306136f;    // s3
        kc[4]  =  42.05869394489765f;    // s4
        kc[5]  = -15.094642576822123f;   // s5
        kc[6]  =   3.8199525848482824f;  // s6
        kc[7]  = -19.739208802178716f;   // c1
        kc[8]  =  64.93939402266829f;    // c2
        kc[9]  = -85.45681720669372f;    // c3
        kc[10] =  60.24464137187665f;    // c4
        kc[11] = -26.426256783358706f;   // c5
        kc[12] =   7.903536371318467f;   // c6
        kc[13] =  -1.714370232222585f;   // c7
    }
}

// Each block: BLK*2 points (2 per thread, v2f-packed) x (NPRIMS/NSPLIT) prims.
// Prim scalars via duplicated SGPR pairs (wave-uniform s_load). sin/cos run
// as packed Taylor polynomials on the main VALU pipe (coeffs in SGPRs);
// only sqrt/exp2 remain on the trans unit.
template <int NSPLIT>
__global__ __launch_bounds__(BLK) void field_kernel(
        const float* __restrict__ qp,
        const PrimDup* __restrict__ pd,
        const float* __restrict__ kc,
        const void* __restrict__ freq_p,
        float2* __restrict__ part) {
    constexpr int PCOUNT = NPRIMS / NSPLIT;        // prims per block
    const int n0 = blockIdx.x * (BLK * 2) + threadIdx.x;
    const int n1 = n0 + BLK;
    const float kr = read_freq(freq_p) / 299792458.0f;   // cycles per metre
    const v2f kr2 = {kr, kr};

    // Poly coefficients: uniform loads -> SGPRs (loop-invariant).
    const float s0 = kc[0], s1 = kc[1], s2 = kc[2], s3 = kc[3];
    const float s4 = kc[4], s5 = kc[5], s6 = kc[6];
    const float c1 = kc[7], c2 = kc[8], c3 = kc[9], c4 = kc[10];
    const float c5 = kc[11], c6 = kc[12], c7 = kc[13];

    // 2 points packed per v2f: lane-local VGPR data, loaded once.
    const v2f xx = {qp[3*n0+0], qp[3*n1+0]};
    const v2f yy = {qp[3*n0+1], qp[3*n1+1]};
    const v2f zz = {qp[3*n0+2], qp[3*n1+2]};

    v2f re = {0.0f, 0.0f}, im = {0.0f, 0.0f};

    const int base = blockIdx.y * PCOUNT;
    #pragma unroll 4
    for (int j = 0; j < PCOUNT; ++j) {
        PrimDup D = pd[base + j];                  // wave-uniform -> s_load x16
        v2f mux = {D.q0.x, D.q0.y}, muy = {D.q0.z, D.q0.w};
        v2f muz = {D.q1.x, D.q1.y}, am2 = {D.q1.z, D.q1.w};   // am2 = -amp
        v2f gx  = {D.q2.x, D.q2.y}, gy  = {D.q2.z, D.q2.w};
        v2f gz  = {D.q3.x, D.q3.y}, ph2 = {D.q3.z, D.q3.w};

        v2f dx = xx - mux, dy = yy - muy, dz = zz - muz;
        v2f t0 = dx * dx, t1 = dy * dy, t2 = dz * dz;
        v2f e  = t0 * gx + t1 * gy + t2 * gz;      // <= 0 (pk_fma chain)
        v2f d2 = t0 + t1 + t2;
        d2 = __builtin_elementwise_max(d2, (v2f){1e-12f, 1e-12f});

        v2f r2 = {__builtin_amdgcn_sqrtf(d2.x), __builtin_amdgcn_sqrtf(d2.y)};  // trans
        v2f ex = {__builtin_amdgcn_exp2f(e.x),  __builtin_amdgcn_exp2f(e.y)};   // trans
        v2f w2 = am2 * ex;                              // = -w (amp negated)
        v2f tp = __builtin_elementwise_fma(kr2, r2, ph2);   // revolutions

        // Range reduce: u = fract(tp) in [0,1), v = u - 0.5 in [-0.5,0.5).
        // sin(2pi*tp) = -sin(2pi*v), cos likewise; the sign lives in w2.
        v2f v = {__builtin_amdgcn_fractf(tp.x), __builtin_amdgcn_fractf(tp.y)};
        v = v - (v2f){0.5f, 0.5f};                 // 0.5 = inline const
        v2f w = v * v;

        v2f ps = __builtin_elementwise_fma(w, (v2f){s6, s6}, (v2f){s5, s5});
        ps = __builtin_elementwise_fma(w, ps, (v2f){s4, s4});
        ps = __builtin_elementwise_fma(w, ps, (v2f){s3, s3});
        ps = __builtin_elementwise_fma(w, ps, (v2f){s2, s2});
        ps = __builtin_elementwise_fma(w, ps, (v2f){s1, s1});
        ps = __builtin_elementwise_fma(w, ps, (v2f){s0, s0});
        v2f sn = v * ps;                            // sin(2pi*v)

        v2f pc = __builtin_elementwise_fma(w, (v2f){c7, c7}, (v2f){c6, c6});
        pc = __builtin_elementwise_fma(w, pc, (v2f){c5, c5});
        pc = __builtin_elementwise_fma(w, pc, (v2f){c4, c4});
        pc = __builtin_elementwise_fma(w, pc, (v2f){c3, c3});
        pc = __builtin_elementwise_fma(w, pc, (v2f){c2, c2});
        pc = __builtin_elementwise_fma(w, pc, (v2f){c1, c1});
        v2f cs = __builtin_elementwise_fma(w, pc, (v2f){1.0f, 1.0f});  // cos(2pi*v)

        re = __builtin_elementwise_fma(w2, cs, re);
        im = __builtin_elementwise_fma(w2, sn, im);
    }

    part[(size_t)blockIdx.y * NPOINTS + n0] = make_float2(re.x, im.x);
    part[(size_t)blockIdx.y * NPOINTS + n1] = make_float2(re.y, im.y);
}

template <int NSPLIT>
__global__ __launch_bounds__(BLK) void reduce_kernel(const float2* __restrict__ part,
                                                     float* __restrict__ out) {
    int n = blockIdx.x * blockDim.x + threadIdx.x;
    float re = 0.0f, im = 0.0f;
    #pragma unroll
    for (int s = 0; s < NSPLIT; ++s) {
        float2 v = part[(size_t)s * NPOINTS + n];
        re += v.x; im += v.y;
    }
    out[n]           = re;   // planar: real block then imag block
    out[NPOINTS + n] = im;
}

// Fallback (tiny workspace): LDS kernel, single pass, direct planar output.
__global__ __launch_bounds__(BLK) void field_fallback(
        const float* __restrict__ qp,
        const float* __restrict__ pos,
        const float* __restrict__ scl,
        const float* __restrict__ amp,
        const float* __restrict__ ph,
        const void*  __restrict__ freq_p,
        float*       __restrict__ out) {
    __shared__ float4 sA[128];
    __shared__ float4 sB[128];
    const int n = blockIdx.x * BLK + threadIdx.x;
    const float x = qp[3*n+0], y = qp[3*n+1], z = qp[3*n+2];
    const float kr = read_freq(freq_p) / 299792458.0f;
    const float KE = -0.72134752044448169f, INV2PI = 0.15915494309189535f;
    float re = 0.0f, im = 0.0f;
    for (int tile = 0; tile < NPRIMS / 128; ++tile) {
        __syncthreads();
        if (threadIdx.x < 128) {
            int p = tile * 128 + threadIdx.x;
            float sx = scl[3*p+0], sy = scl[3*p+1], sz = scl[3*p+2];
            sA[threadIdx.x] = make_float4(pos[3*p+0], pos[3*p+1], pos[3*p+2], amp[p]);
            sB[threadIdx.x] = make_float4(KE/(sx*sx), KE/(sy*sy), KE/(sz*sz), ph[p]*INV2PI);
        }
        __syncthreads();
        #pragma unroll 8
        for (int p = 0; p < 128; ++p) {
            float4 a = sA[p];
            float4 b = sB[p];
            float dx = x - a.x, dy = y - a.y, dz = z - a.z;
            float t0 = dx*dx, t1 = dy*dy, t2 = dz*dz;
            float e  = fmaf(t0, b.x, fmaf(t1, b.y, t2 * b.z));
            float d2 = t0 + t1 + t2;
            float r  = __builtin_amdgcn_sqrtf(fmaxf(d2, 1e-12f));
            float w  = a.w * __builtin_amdgcn_exp2f(e);
            float tp = __builtin_amdgcn_fractf(fmaf(kr, r, b.w));
            float s  = __builtin_amdgcn_sinf(tp);
            float c  = __builtin_amdgcn_cosf(tp);
            re = fmaf(w, c, re);
            im = fmaf(w, s, im);
        }
    }
    out[n]           = re;
    out[NPOINTS + n] = im;
}

extern "C" void kernel_launch(void* const* d_in, const int* in_sizes, int n_in,
                              void* d_out, int out_size, void* d_ws, size_t ws_size,
                              hipStream_t stream) {
    const float* qp  = (const float*)d_in[0];
    const float* pos = (const float*)d_in[1];
    const float* scl = (const float*)d_in[2];
    const float* amp = (const float*)d_in[3];
    const float* ph  = (const float*)d_in[4];
    const void*  fq  = d_in[5];
    float* out = (float*)d_out;

    const size_t packed_bytes = (size_t)NPRIMS * sizeof(PrimDup);   // 128 KB
    const size_t coeff_bytes  = 256;                                 // 14 floats, padded
    const size_t head = packed_bytes + coeff_bytes;
    const size_t ps32 = head + (size_t)32 * NPOINTS * sizeof(float2); // +8 MB
    const size_t ps16 = head + (size_t)16 * NPOINTS * sizeof(float2); // +4 MB

    if (ws_size >= ps32) {
        PrimDup* pd   = (PrimDup*)d_ws;
        float*   kc   = (float*)((char*)d_ws + packed_bytes);
        float2*  part = (float2*)((char*)d_ws + head);
        prep_kernel<<<dim3(NPRIMS / BLK), dim3(BLK), 0, stream>>>(pos, scl, amp, ph, pd, kc);
        field_kernel<32><<<dim3(NPOINTS / (BLK * 2), 32), dim3(BLK), 0, stream>>>(qp, pd, kc, fq, part);
        reduce_kernel<32><<<dim3(NPOINTS / BLK), dim3(BLK), 0, stream>>>(part, out);
    } else if (ws_size >= ps16) {
        PrimDup* pd   = (PrimDup*)d_ws;
        float*   kc   = (float*)((char*)d_ws + packed_bytes);
        float2*  part = (float2*)((char*)d_ws + head);
        prep_kernel<<<dim3(NPRIMS / BLK), dim3(BLK), 0, stream>>>(pos, scl, amp, ph, pd, kc);
        field_kernel<16><<<dim3(NPOINTS / (BLK * 2), 16), dim3(BLK), 0, stream>>>(qp, pd, kc, fq, part);
        reduce_kernel<16><<<dim3(NPOINTS / BLK), dim3(BLK), 0, stream>>>(part, out);
    } else {
        field_fallback<<<dim3(NPOINTS / BLK), dim3(BLK), 0, stream>>>(qp, pos, scl, amp, ph, fq, out);
    }
}

// Round 12
// 55.854 us; speedup vs baseline: 1.1461x; 1.1461x over previous
//
#include <hip/hip_runtime.h>
#include <math.h>

#define NPOINTS 32768
#define NPRIMS  2048
#define BLK     256

typedef float v2f __attribute__((ext_vector_type(2)));

// 64-byte record for ONE primitive, every scalar DUPLICATED so an s_load'd
// even-aligned SGPR pair feeds VOP3P packed ops as a broadcast operand.
//  q0 = (mux, mux, muy, muy)
//  q1 = (muz, muz, amp, amp)
//  q2 = (gx,  gx,  gy,  gy )     g = -0.5*log2(e)/s^2
//  q3 = (gz,  gz,  ph,  ph )     ph in revolutions (phase/2pi)
struct PrimDup { float4 q0, q1, q2, q3; };

// Robust scalar-frequency decode (2400000000 in any plausible encoding).
__device__ __forceinline__ float read_freq(const void* p) {
    const unsigned* w = (const unsigned*)p;
    unsigned lo = w[0];
    float ff = __uint_as_float(lo);
    if (ff >= 1.0e5f && ff <= 1.0e13f) return ff;       // float32
    if (lo != 0u) return (float)lo;                      // int32-wrap / int64 lo
    double d = *(const double*)p;                        // lo==0 -> 8-byte dtype
    if (d >= 1.0e5 && d <= 1.0e13) return (float)d;      // float64
    unsigned long long v = ((unsigned long long)w[1] << 32) | lo;
    return (float)v;                                     // int64 (hi-word path)
}

__global__ __launch_bounds__(BLK) void prep_kernel(
        const float* __restrict__ pos,
        const float* __restrict__ scl,
        const float* __restrict__ amp,
        const float* __restrict__ ph,
        PrimDup* __restrict__ pd) {
    int p = blockIdx.x * blockDim.x + threadIdx.x;
    if (p >= NPRIMS) return;
    const float KE     = -0.72134752044448169f;   // -0.5*log2(e)
    const float INV2PI =  0.15915494309189535f;
    float sx = scl[3*p+0], sy = scl[3*p+1], sz = scl[3*p+2];
    float gx = KE / (sx*sx), gy = KE / (sy*sy), gz = KE / (sz*sz);
    float pr = ph[p] * INV2PI;
    PrimDup D;
    D.q0 = make_float4(pos[3*p+0], pos[3*p+0], pos[3*p+1], pos[3*p+1]);
    D.q1 = make_float4(pos[3*p+2], pos[3*p+2], amp[p], amp[p]);
    D.q2 = make_float4(gx, gx, gy, gy);
    D.q3 = make_float4(gz, gz, pr, pr);
    pd[p] = D;
}

// Each block: BLK*2*NPAIR points x (NPRIMS/NSPLIT) prims. NPAIR independent
// v2f point-pairs per thread give the scheduler independent chains to
// interleave (hide trans/s_load latency with ILP, not just occupancy).
// Prim scalars via duplicated SGPR pairs (wave-uniform s_load, broadcast
// operands into VOP3P — no v_mov assembly). hw trig path (R10-verified).
template <int NSPLIT, int NPAIR>
__global__ __launch_bounds__(BLK) void field_kernel(
        const float* __restrict__ qp,
        const PrimDup* __restrict__ pd,
        const void* __restrict__ freq_p,
        float2* __restrict__ part) {
    constexpr int PCOUNT = NPRIMS / NSPLIT;        // prims per block
    const int n0 = blockIdx.x * (BLK * 2 * NPAIR) + threadIdx.x;
    const float kr = read_freq(freq_p) / 299792458.0f;   // cycles per metre
    const v2f kr2 = {kr, kr};

    v2f xx[NPAIR], yy[NPAIR], zz[NPAIR], re[NPAIR], im[NPAIR];
    #pragma unroll
    for (int i = 0; i < NPAIR; ++i) {
        int a = n0 + (2 * i) * BLK;
        int b = n0 + (2 * i + 1) * BLK;
        xx[i] = (v2f){qp[3*a+0], qp[3*b+0]};
        yy[i] = (v2f){qp[3*a+1], qp[3*b+1]};
        zz[i] = (v2f){qp[3*a+2], qp[3*b+2]};
        re[i] = (v2f){0.0f, 0.0f};
        im[i] = (v2f){0.0f, 0.0f};
    }

    const int base = blockIdx.y * PCOUNT;
    #pragma unroll 2
    for (int j = 0; j < PCOUNT; ++j) {
        PrimDup D = pd[base + j];                  // wave-uniform -> s_load x16
        v2f mux = {D.q0.x, D.q0.y}, muy = {D.q0.z, D.q0.w};
        v2f muz = {D.q1.x, D.q1.y}, am2 = {D.q1.z, D.q1.w};
        v2f gx  = {D.q2.x, D.q2.y}, gy  = {D.q2.z, D.q2.w};
        v2f gz  = {D.q3.x, D.q3.y}, ph2 = {D.q3.z, D.q3.w};

        #pragma unroll
        for (int i = 0; i < NPAIR; ++i) {          // independent chains
            v2f dx = xx[i] - mux, dy = yy[i] - muy, dz = zz[i] - muz;
            v2f t0 = dx * dx, t1 = dy * dy, t2 = dz * dz;
            v2f e  = t0 * gx + t1 * gy + t2 * gz;  // <= 0 (pk_fma chain)
            v2f d2 = t0 + t1 + t2;
            d2 = __builtin_elementwise_max(d2, (v2f){1e-12f, 1e-12f});

            v2f r2 = {__builtin_amdgcn_sqrtf(d2.x), __builtin_amdgcn_sqrtf(d2.y)};
            v2f ex = {__builtin_amdgcn_exp2f(e.x),  __builtin_amdgcn_exp2f(e.y)};
            v2f w2 = am2 * ex;
            v2f tp = __builtin_elementwise_fma(kr2, r2, ph2);   // revolutions
            float f0 = __builtin_amdgcn_fractf(tp.x);
            float f1 = __builtin_amdgcn_fractf(tp.y);
            v2f s2 = {__builtin_amdgcn_sinf(f0), __builtin_amdgcn_sinf(f1)};
            v2f c2 = {__builtin_amdgcn_cosf(f0), __builtin_amdgcn_cosf(f1)};
            re[i] = __builtin_elementwise_fma(w2, c2, re[i]);
            im[i] = __builtin_elementwise_fma(w2, s2, im[i]);
        }
    }

    #pragma unroll
    for (int i = 0; i < NPAIR; ++i) {
        int a = n0 + (2 * i) * BLK;
        int b = n0 + (2 * i + 1) * BLK;
        part[(size_t)blockIdx.y * NPOINTS + a] = make_float2(re[i].x, im[i].x);
        part[(size_t)blockIdx.y * NPOINTS + b] = make_float2(re[i].y, im[i].y);
    }
}

template <int NSPLIT>
__global__ __launch_bounds__(BLK) void reduce_kernel(const float2* __restrict__ part,
                                                     float* __restrict__ out) {
    int n = blockIdx.x * blockDim.x + threadIdx.x;
    float re = 0.0f, im = 0.0f;
    #pragma unroll
    for (int s = 0; s < NSPLIT; ++s) {
        float2 v = part[(size_t)s * NPOINTS + n];
        re += v.x; im += v.y;
    }
    out[n]           = re;   // planar: real block then imag block
    out[NPOINTS + n] = im;
}

// Fallback (tiny workspace): LDS kernel, single pass, direct planar output.
__global__ __launch_bounds__(BLK) void field_fallback(
        const float* __restrict__ qp,
        const float* __restrict__ pos,
        const float* __restrict__ scl,
        const float* __restrict__ amp,
        const float* __restrict__ ph,
        const void*  __restrict__ freq_p,
        float*       __restrict__ out) {
    __shared__ float4 sA[128];
    __shared__ float4 sB[128];
    const int n = blockIdx.x * BLK + threadIdx.x;
    const float x = qp[3*n+0], y = qp[3*n+1], z = qp[3*n+2];
    const float kr = read_freq(freq_p) / 299792458.0f;
    const float KE = -0.72134752044448169f, INV2PI = 0.15915494309189535f;
    float re = 0.0f, im = 0.0f;
    for (int tile = 0; tile < NPRIMS / 128; ++tile) {
        __syncthreads();
        if (threadIdx.x < 128) {
            int p = tile * 128 + threadIdx.x;
            float sx = scl[3*p+0], sy = scl[3*p+1], sz = scl[3*p+2];
            sA[threadIdx.x] = make_float4(pos[3*p+0], pos[3*p+1], pos[3*p+2], amp[p]);
            sB[threadIdx.x] = make_float4(KE/(sx*sx), KE/(sy*sy), KE/(sz*sz), ph[p]*INV2PI);
        }
        __syncthreads();
        #pragma unroll 8
        for (int p = 0; p < 128; ++p) {
            float4 a = sA[p];
            float4 b = sB[p];
            float dx = x - a.x, dy = y - a.y, dz = z - a.z;
            float t0 = dx*dx, t1 = dy*dy, t2 = dz*dz;
            float e  = fmaf(t0, b.x, fmaf(t1, b.y, t2 * b.z));
            float d2 = t0 + t1 + t2;
            float r  = __builtin_amdgcn_sqrtf(fmaxf(d2, 1e-12f));
            float w  = a.w * __builtin_amdgcn_exp2f(e);
            float tp = __builtin_amdgcn_fractf(fmaf(kr, r, b.w));
            float s  = __builtin_amdgcn_sinf(tp);
            float c  = __builtin_amdgcn_cosf(tp);
            re = fmaf(w, c, re);
            im = fmaf(w, s, im);
        }
    }
    out[n]           = re;
    out[NPOINTS + n] = im;
}

extern "C" void kernel_launch(void* const* d_in, const int* in_sizes, int n_in,
                              void* d_out, int out_size, void* d_ws, size_t ws_size,
                              hipStream_t stream) {
    const float* qp  = (const float*)d_in[0];
    const float* pos = (const float*)d_in[1];
    const float* scl = (const float*)d_in[2];
    const float* amp = (const float*)d_in[3];
    const float* ph  = (const float*)d_in[4];
    const void*  fq  = d_in[5];
    float* out = (float*)d_out;

    const size_t packed_bytes = (size_t)NPRIMS * sizeof(PrimDup);            // 128 KB
    const size_t ps64 = packed_bytes + (size_t)64 * NPOINTS * sizeof(float2); // +16 MB
    const size_t ps32 = packed_bytes + (size_t)32 * NPOINTS * sizeof(float2); // +8 MB

    if (ws_size >= ps64) {
        // 2048 blocks (32 chunks x 64 splits), 4 points/thread (2 v2f pairs)
        PrimDup* pd   = (PrimDup*)d_ws;
        float2*  part = (float2*)((char*)d_ws + packed_bytes);
        prep_kernel<<<dim3(NPRIMS / BLK), dim3(BLK), 0, stream>>>(pos, scl, amp, ph, pd);
        field_kernel<64, 2><<<dim3(NPOINTS / (BLK * 4), 64), dim3(BLK), 0, stream>>>(qp, pd, fq, part);
        reduce_kernel<64><<<dim3(NPOINTS / BLK), dim3(BLK), 0, stream>>>(part, out);
    } else if (ws_size >= ps32) {
        // exact round-10 configuration (known 44.1 us field)
        PrimDup* pd   = (PrimDup*)d_ws;
        float2*  part = (float2*)((char*)d_ws + packed_bytes);
        prep_kernel<<<dim3(NPRIMS / BLK), dim3(BLK), 0, stream>>>(pos, scl, amp, ph, pd);
        field_kernel<32, 1><<<dim3(NPOINTS / (BLK * 2), 32), dim3(BLK), 0, stream>>>(qp, pd, fq, part);
        reduce_kernel<32><<<dim3(NPOINTS / BLK), dim3(BLK), 0, stream>>>(part, out);
    } else {
        field_fallback<<<dim3(NPOINTS / BLK), dim3(BLK), 0, stream>>>(qp, pos, scl, amp, ph, fq, out);
    }
}